// Round 11
// baseline (49444.168 us; speedup 1.0000x reference)
//
#include <hip/hip_runtime.h>

// Problem constants
#define Hh   512
#define Vv   128
#define LL   8192
#define G3   1536      // 3*H
#define NBK  256       // 128 layer-0 blocks + 128 layer-1 blocks, 64 thr each
#define S0   64        // h0 ring slots (gate every 32 ticks, slack 16: S0>=47)
#define S1   4         // h1 ring slots (layer-1 mutual skew <= 1)

// workspace layout (bytes). record = h0ring(64*512 pairs) ++ h1ring(4*512)
#define RECBYTES ((S0*512 + S1*512) * 8ull)            // 278,528
#define OFF_GX   0ull                                  // 50,331,648
#define OFF_YS   50331648ull                           // 16,777,216
#define OFF_RECE 67108864ull
#define OFF_RECD (OFF_RECE + RECBYTES)
#define OFF_WT   (OFF_RECD + RECBYTES)                 // 262,144

#define H1OFF (S0*512)   // pair offset of h1 ring within a record

__device__ __forceinline__ float sigm(float x)  { return 1.f / (1.f + __expf(-x)); }
__device__ __forceinline__ float tanha(float x) { return 2.f / (1.f + __expf(-2.f * x)) - 1.f; }

__device__ __forceinline__ unsigned long long packpair(float v, int t) {
    return ((unsigned long long)(unsigned)t << 32) | (unsigned long long)__float_as_uint(v);
}
__device__ __forceinline__ int   pair_tag(unsigned long long p) { return (int)(p >> 32); }
__device__ __forceinline__ float pair_val(unsigned long long p) { return __uint_as_float((unsigned)p); }

template <int CTRL>
__device__ __forceinline__ float dpp_add(float m) {
    int t = __builtin_amdgcn_update_dpp(0, __builtin_bit_cast(int, m), CTRL, 0xF, 0xF, true);
    return m + __builtin_bit_cast(float, t);
}
// pair-merged butterfly: returns row-2k sum on even lanes / row-2k+1 on odd
__device__ __forceinline__ float red2(float a, float c, int lane) {
    a = dpp_add<0xB1>(a);
    c = dpp_add<0xB1>(c);
    float m = (lane & 1) ? c : a;
    m = dpp_add<0x122>(m);
    m = dpp_add<0x124>(m);
    m = dpp_add<0x128>(m);
    m += __shfl_xor(m, 16);
    m += __shfl_xor(m, 32);
    return m;
}

// ---------------------------------------------------------------------------
// gx = X @ Wih^T + bih
// ---------------------------------------------------------------------------
__global__ __launch_bounds__(256) void gemm_gx(
    const float* __restrict__ X, const float* __restrict__ Wih,
    const float* __restrict__ bih, float* __restrict__ gxo, int shift_relu)
{
    __shared__ float xs[16][128];
    const int tid = threadIdx.x;
    const int m0  = blockIdx.x * 16;
    const int c   = blockIdx.y * 256 + tid;

    for (int i = tid; i < 16 * 128; i += 256) {
        const int r = i >> 7, k = i & 127;
        int srow = m0 + r;
        if (shift_relu) srow = (srow == 0) ? 0 : (srow - 1);
        float v = X[(size_t)srow * Vv + k];
        if (shift_relu) v = fmaxf(v, 0.f);
        xs[r][k] = v;
    }
    __syncthreads();

    const float4* wp = (const float4*)(Wih + (size_t)c * Vv);
    float4 wr[32];
#pragma unroll
    for (int q = 0; q < 32; ++q) wr[q] = wp[q];
    const float bb = bih[c];

    for (int m = 0; m < 16; ++m) {
        const float4* xp = (const float4*)xs[m];
        float acc = bb;
#pragma unroll
        for (int q = 0; q < 32; ++q) {
            const float4 x4 = xp[q];
            acc = fmaf(wr[q].x, x4.x, acc); acc = fmaf(wr[q].y, x4.y, acc);
            acc = fmaf(wr[q].z, x4.z, acc); acc = fmaf(wr[q].w, x4.w, acc);
        }
        gxo[(size_t)(m0 + m) * G3 + c] = acc;
    }
}

// ---------------------------------------------------------------------------
// Split-role persistent GRU scan with CONSUME-ON-ARRIVAL polling.
// Blocks 0-127: layer 0 (own h0[4b..4b+3]); blocks 128-255: layer 1.
// h0 ring: 64 slots (slot t&63, tag t); h1 ring: 4 slots. Poll loops FMA
// each pair the round it arrives, in strict prefix order j=0..7 (fixed
// summation order -> deterministic output), hiding compute inside the spin
// for stragglers. Layer-0 gates on the layer-1 watermark every 32 ticks
// (h1 slot t&3 tag >= t-16; safe: S0=64 >= 32+16-1, layer-1 lag <= 48 < 64).
// All pairs self-validating (value,tag); protocol otherwise as rounds 3-10.
// ---------------------------------------------------------------------------
__global__ __launch_bounds__(64, 1) void seq2(
    const float* __restrict__ gx,
    const float* __restrict__ Whh0, const float* __restrict__ Wih1,
    const float* __restrict__ Whh1,
    const float* __restrict__ bhh0, const float* __restrict__ bih1,
    const float* __restrict__ bhh1,
    unsigned long long* __restrict__ rec,
    float* __restrict__ ys)
{
    const int bid = blockIdx.x, lane = threadIdx.x;
    unsigned long long* h0rec = rec;
    unsigned long long* h1rec = rec + H1OFF;

    if (bid < 128) {
        // ================= layer 0 =================
        const int e0 = 4 * bid;
        int off[8];
#pragma unroll
        for (int j = 0; j < 8; ++j) off[j] = (e0 + lane + 64 * j) & 511;

        float w[12][8];   // rows r = 4*g + i  (Whh0)
#pragma unroll
        for (int g = 0; g < 3; ++g)
#pragma unroll
            for (int i = 0; i < 4; ++i) {
                const float* row = Whh0 + (size_t)(g * Hh + e0 + i) * Hh;
#pragma unroll
                for (int j = 0; j < 8; ++j) w[g * 4 + i][j] = row[off[j]];
            }

        float b_r = 0.f, b_z = 0.f, b_n = 0.f;
        if (lane < 4) {
            const int e = e0 + lane;
            b_r = bhh0[e]; b_z = bhh0[Hh + e]; b_n = bhh0[2 * Hh + e];
        }
        float xr = 0.f, xz = 0.f, xn = 0.f;
        if (lane < 4) {
            xr = gx[e0 + lane]; xz = gx[Hh + e0 + lane]; xn = gx[2 * Hh + e0 + lane];
        }

        for (int t = 0; t < LL; ++t) {
            // consume-on-arrival spin on h0(t-1): prefix-order FMA
            const int need = t - 1;
            const unsigned long long* rp = h0rec + (size_t)((t + S0 - 1) & (S0 - 1)) * 512;
            float acc[12];
#pragma unroll
            for (int r = 0; r < 12; ++r) acc[r] = 0.f;
            float h0self = 0.f;
            unsigned done = 0;
            do {
                unsigned long long p[8];
#pragma unroll
                for (int j = 0; j < 8; ++j)
                    p[j] = __hip_atomic_load(rp + off[j], __ATOMIC_RELAXED, __HIP_MEMORY_SCOPE_AGENT);
#pragma unroll
                for (int j = 0; j < 8; ++j) {
                    if (done == (unsigned)j && pair_tag(p[j]) >= need) {
                        const float v = pair_val(p[j]);
                        if (j == 0) h0self = v;
#pragma unroll
                        for (int r = 0; r < 12; ++r) acc[r] = fmaf(w[r][j], v, acc[r]);
                        done = j + 1;
                    }
                }
            } while (!__all(done == 8u));

            // layer-1 watermark gate, once per 32 ticks (16-tick slack)
            if ((t & 31) == 0) {
                const int gneed = t - 16;
                const unsigned long long* gp = h1rec + (size_t)(t & (S1 - 1)) * 512;
                int gok;
                do {
                    gok = 1;
#pragma unroll
                    for (int j = 0; j < 8; ++j) {
                        const unsigned long long q = __hip_atomic_load(
                            gp + ((lane + 64 * j) & 511), __ATOMIC_RELAXED, __HIP_MEMORY_SCOPE_AGENT);
                        gok &= (pair_tag(q) >= gneed);
                    }
                } while (!__all(gok));
            }

            // prefetch next gx row (hides under next spin)
            float nxr = 0.f, nxz = 0.f, nxn = 0.f;
            if (lane < 4 && t + 1 < LL) {
                const size_t gb = (size_t)(t + 1) * G3 + e0 + lane;
                nxr = gx[gb]; nxz = gx[gb + Hh]; nxn = gx[gb + 2 * Hh];
            }

            float sred[6];
#pragma unroll
            for (int k = 0; k < 6; ++k) sred[k] = red2(acc[2 * k], acc[2 * k + 1], lane);

            if (lane < 4) {
                const int i2 = lane >> 1;
                const float rg = sigm(xr + sred[i2] + b_r);
                const float zg = sigm(xz + sred[2 + i2] + b_z);
                const float ng = tanha(xn + rg * (sred[4 + i2] + b_n));
                const float hnew = (1.f - zg) * ng + zg * h0self;
                __hip_atomic_store(h0rec + (size_t)(t & (S0 - 1)) * 512 + e0 + lane,
                                   packpair(hnew, t), __ATOMIC_RELAXED, __HIP_MEMORY_SCOPE_AGENT);
            }
            xr = nxr; xz = nxz; xn = nxn;
        }
    } else {
        // ================= layer 1 =================
        const int e0 = 4 * (bid - 128);
        int off[8];
#pragma unroll
        for (int j = 0; j < 8; ++j) off[j] = (e0 + lane + 64 * j) & 511;

        float wA[12][8], wB[12][8];   // Wih1, Whh1; rows r = 4*g + i
#pragma unroll
        for (int g = 0; g < 3; ++g)
#pragma unroll
            for (int i = 0; i < 4; ++i) {
                const float* rowA = Wih1 + (size_t)(g * Hh + e0 + i) * Hh;
                const float* rowB = Whh1 + (size_t)(g * Hh + e0 + i) * Hh;
#pragma unroll
                for (int j = 0; j < 8; ++j) {
                    wA[g * 4 + i][j] = rowA[off[j]];
                    wB[g * 4 + i][j] = rowB[off[j]];
                }
            }

        float b_r = 0.f, b_z = 0.f, b_n1 = 0.f, b_n2 = 0.f;
        if (lane < 4) {
            const int e = e0 + lane;
            b_r  = bih1[e] + bhh1[e];
            b_z  = bih1[Hh + e] + bhh1[Hh + e];
            b_n1 = bih1[2 * Hh + e];
            b_n2 = bhh1[2 * Hh + e];
        }

        for (int t = 0; t < LL; ++t) {
            // consume-on-arrival over h0(t) [wA] and h1(t-1) [wB], separate
            // accumulators (fixed per-source summation order -> deterministic)
            const unsigned long long* rp0 = h0rec + (size_t)(t & (S0 - 1)) * 512;
            const unsigned long long* rp1 = h1rec + (size_t)((t + S1 - 1) & (S1 - 1)) * 512;
            float accA[12], accB[12];
#pragma unroll
            for (int r = 0; r < 12; ++r) { accA[r] = 0.f; accB[r] = 0.f; }
            float h1self = 0.f;
            unsigned d0 = 0, d1 = 0;
            do {
                unsigned long long q0[8], q1[8];
#pragma unroll
                for (int j = 0; j < 8; ++j)
                    q0[j] = __hip_atomic_load(rp0 + off[j], __ATOMIC_RELAXED, __HIP_MEMORY_SCOPE_AGENT);
#pragma unroll
                for (int j = 0; j < 8; ++j)
                    q1[j] = __hip_atomic_load(rp1 + off[j], __ATOMIC_RELAXED, __HIP_MEMORY_SCOPE_AGENT);
#pragma unroll
                for (int j = 0; j < 8; ++j) {
                    if (d0 == (unsigned)j && pair_tag(q0[j]) >= t) {
                        const float v = pair_val(q0[j]);
#pragma unroll
                        for (int r = 0; r < 12; ++r) accA[r] = fmaf(wA[r][j], v, accA[r]);
                        d0 = j + 1;
                    }
                    if (d1 == (unsigned)j && pair_tag(q1[j]) >= t - 1) {
                        const float v = pair_val(q1[j]);
                        if (j == 0) h1self = v;
#pragma unroll
                        for (int r = 0; r < 12; ++r) accB[r] = fmaf(wB[r][j], v, accB[r]);
                        d1 = j + 1;
                    }
                }
            } while (!__all((d0 == 8u) & (d1 == 8u)));

            // reductions: r/z gates = A+B (rows 0..7), nA rows 8..11, nB rows 8..11
            float sred[8];
#pragma unroll
            for (int k = 0; k < 4; ++k)
                sred[k] = red2(accA[2 * k] + accB[2 * k], accA[2 * k + 1] + accB[2 * k + 1], lane);
#pragma unroll
            for (int k = 0; k < 2; ++k) {
                sred[4 + k] = red2(accA[8 + 2 * k], accA[9 + 2 * k], lane);
                sred[6 + k] = red2(accB[8 + 2 * k], accB[9 + 2 * k], lane);
            }

            if (lane < 4) {
                const int i2 = lane >> 1;
                const float rg = sigm(sred[i2] + b_r);
                const float zg = sigm(sred[2 + i2] + b_z);
                const float ng = tanha(sred[4 + i2] + b_n1 + rg * (sred[6 + i2] + b_n2));
                const float hnew = (1.f - zg) * ng + zg * h1self;
                if (ys) ys[(size_t)t * Hh + e0 + lane] = hnew;
                __hip_atomic_store(h1rec + (size_t)(t & (S1 - 1)) * 512 + e0 + lane,
                                   packpair(hnew, t), __ATOMIC_RELAXED, __HIP_MEMORY_SCOPE_AGENT);
            }
        }
    }
}

// ---------------------------------------------------------------------------
// WoutT + encoder record init. h0 ring: slot 63 = (0, tag -1), others -100.
// h1 ring: slot 3 = (0, tag -1), slots 0..2 = tags -4,-3,-2.
// ---------------------------------------------------------------------------
__global__ __launch_bounds__(256) void transposeW(const float* __restrict__ W,
                                                  float* __restrict__ WT,
                                                  unsigned long long* __restrict__ encr)
{
    const int i = blockIdx.x * 256 + threadIdx.x;  // 0..65535
    WT[(i & 511) * 128 + (i >> 9)] = W[i];
    if (i < S0 * 512) {
        const int slot = i >> 9;
        __hip_atomic_store(encr + i, packpair(0.f, (slot == S0 - 1) ? -1 : -100),
                           __ATOMIC_RELAXED, __HIP_MEMORY_SCOPE_AGENT);
    }
    if (i < S1 * 512) {
        const int slot = i >> 9;
        __hip_atomic_store(encr + H1OFF + i, packpair(0.f, (slot == S1 - 1) ? -1 : slot - 4),
                           __ATOMIC_RELAXED, __HIP_MEMORY_SCOPE_AGENT);
    }
}

// ---------------------------------------------------------------------------
// encoder -> decoder handoff. enc h0(8191): slot 8191&63 = 63; enc h1(8191):
// slot 3. Rewrite EVERY decoder slot (stale tags from prior replay must die).
// ---------------------------------------------------------------------------
__global__ __launch_bounds__(256) void handoff(const unsigned long long* __restrict__ encr,
                                               unsigned long long* __restrict__ decr)
{
    const int p = blockIdx.x * 256 + threadIdx.x;  // 0..32767
    {
        const int slot = p >> 9;
        unsigned long long v;
        if (slot == S0 - 1) {
            const unsigned long long src = __hip_atomic_load(
                encr + p, __ATOMIC_RELAXED, __HIP_MEMORY_SCOPE_AGENT);
            v = packpair(pair_val(src), -1);
        } else {
            v = packpair(0.f, -100);
        }
        __hip_atomic_store(decr + p, v, __ATOMIC_RELAXED, __HIP_MEMORY_SCOPE_AGENT);
    }
    if (p < S1 * 512) {
        const int slot = p >> 9;
        unsigned long long v;
        if (slot == S1 - 1) {
            const unsigned long long src = __hip_atomic_load(
                encr + H1OFF + p, __ATOMIC_RELAXED, __HIP_MEMORY_SCOPE_AGENT);
            v = packpair(pair_val(src), -1);
        } else {
            v = packpair(0.f, slot - 4);
        }
        __hip_atomic_store(decr + H1OFF + p, v, __ATOMIC_RELAXED, __HIP_MEMORY_SCOPE_AGENT);
    }
}

// ---------------------------------------------------------------------------
// out = sigmoid(ys @ Wout^T + bout)
// ---------------------------------------------------------------------------
__global__ __launch_bounds__(128) void out_proj(
    const float* __restrict__ ys, const float* __restrict__ WT,
    const float* __restrict__ bout, float* __restrict__ out)
{
    __shared__ float yss[16][512];
    const int tid = threadIdx.x;
    const int m0  = blockIdx.x * 16;

    for (int i = tid; i < 16 * 512; i += 128)
        yss[i >> 9][i & 511] = ys[(size_t)(m0 + (i >> 9)) * 512 + (i & 511)];
    __syncthreads();

    const int c = tid;
    float acc[16];
    const float b = bout[c];
#pragma unroll
    for (int m = 0; m < 16; ++m) acc[m] = b;

    for (int k4 = 0; k4 < 128; ++k4) {
        const float w0 = WT[(4 * k4 + 0) * 128 + c];
        const float w1 = WT[(4 * k4 + 1) * 128 + c];
        const float w2 = WT[(4 * k4 + 2) * 128 + c];
        const float w3 = WT[(4 * k4 + 3) * 128 + c];
#pragma unroll
        for (int m = 0; m < 16; ++m) {
            const float4 yv = *(const float4*)&yss[m][4 * k4];
            acc[m] = fmaf(w0, yv.x, fmaf(w1, yv.y, fmaf(w2, yv.z, fmaf(w3, yv.w, acc[m]))));
        }
    }
#pragma unroll
    for (int m = 0; m < 16; ++m)
        out[(size_t)(m0 + m) * 128 + c] = 1.f / (1.f + __expf(-acc[m]));
}

// ---------------------------------------------------------------------------
extern "C" void kernel_launch(void* const* d_in, const int* in_sizes, int n_in,
                              void* d_out, int out_size, void* d_ws, size_t ws_size,
                              hipStream_t stream)
{
    const float* src      = (const float*)d_in[0];
    const float* trg      = (const float*)d_in[1];
    const float* eWih0    = (const float*)d_in[2];
    const float* eWhh0    = (const float*)d_in[3];
    const float* ebih0    = (const float*)d_in[4];
    const float* ebhh0    = (const float*)d_in[5];
    const float* eWih1    = (const float*)d_in[6];
    const float* eWhh1    = (const float*)d_in[7];
    const float* ebih1    = (const float*)d_in[8];
    const float* ebhh1    = (const float*)d_in[9];
    const float* dWih0    = (const float*)d_in[10];
    const float* dWhh0    = (const float*)d_in[11];
    const float* dbih0    = (const float*)d_in[12];
    const float* dbhh0    = (const float*)d_in[13];
    const float* dWih1    = (const float*)d_in[14];
    const float* dWhh1    = (const float*)d_in[15];
    const float* dbih1    = (const float*)d_in[16];
    const float* dbhh1    = (const float*)d_in[17];
    const float* Wout     = (const float*)d_in[18];
    const float* bout     = (const float*)d_in[19];

    char* ws = (char*)d_ws;
    float*              gx   = (float*)(ws + OFF_GX);
    float*              ys   = (float*)(ws + OFF_YS);
    unsigned long long* recE = (unsigned long long*)(ws + OFF_RECE);
    unsigned long long* recD = (unsigned long long*)(ws + OFF_RECD);
    float*              WT   = (float*)(ws + OFF_WT);

    hipLaunchKernelGGL(transposeW, dim3(256), dim3(256), 0, stream, Wout, WT, recE);

    // ---- encoder ----
    hipLaunchKernelGGL(gemm_gx, dim3(LL / 16, 6), dim3(256), 0, stream,
                       src, eWih0, ebih0, gx, 0);
    hipLaunchKernelGGL(seq2, dim3(NBK), dim3(64), 0, stream,
                       gx, eWhh0, eWih1, eWhh1, ebhh0, ebih1, ebhh1,
                       recE, (float*)nullptr);

    // ---- handoff + decoder ----
    hipLaunchKernelGGL(handoff, dim3(128), dim3(256), 0, stream, recE, recD);
    hipLaunchKernelGGL(gemm_gx, dim3(LL / 16, 6), dim3(256), 0, stream,
                       trg, dWih0, dbih0, gx, 1);
    hipLaunchKernelGGL(seq2, dim3(NBK), dim3(64), 0, stream,
                       gx, dWhh0, dWih1, dWhh1, dbhh0, dbih1, dbhh1,
                       recD, ys);

    // ---- output projection ----
    hipLaunchKernelGGL(out_proj, dim3(LL / 16), dim3(128), 0, stream,
                       ys, WT, bout, (float*)d_out);

    (void)in_sizes; (void)n_in; (void)out_size; (void)ws_size;
}

// Round 13
// 35005.731 us; speedup vs baseline: 1.4125x; 1.4125x over previous
//
#include <hip/hip_runtime.h>

// Problem constants
#define Hh   512
#define Vv   128
#define LL   8192
#define G3   1536      // 3*H
#define NBK  256       // 128 layer-0 blocks + 128 layer-1 blocks, 64 thr each
#define S0   64        // h0 ring slots (gate every 32 ticks, slack 16)
#define S1   4         // h1 ring slots

// workspace layout (bytes). record = h0ring(64*512 pairs) ++ h1ring(4*512)
#define RECBYTES ((S0*512 + S1*512) * 8ull)            // 278,528
#define OFF_GX   0ull                                  // 50,331,648
#define OFF_YS   50331648ull                           // 16,777,216
#define OFF_RECE 67108864ull
#define OFF_RECD (OFF_RECE + RECBYTES)
#define OFF_WT   (OFF_RECD + RECBYTES)                 // 262,144

#define H1OFF (S0*512)   // pair offset of h1 ring within a record

__device__ __forceinline__ float sigm(float x)  { return 1.f / (1.f + __expf(-x)); }
__device__ __forceinline__ float tanha(float x) { return 2.f / (1.f + __expf(-2.f * x)) - 1.f; }

__device__ __forceinline__ unsigned long long packpair(float v, int t) {
    return ((unsigned long long)(unsigned)t << 32) | (unsigned long long)__float_as_uint(v);
}
__device__ __forceinline__ int   pair_tag(unsigned long long p) { return (int)(p >> 32); }
__device__ __forceinline__ float pair_val(unsigned long long p) { return __uint_as_float((unsigned)p); }

#define ALOAD(p) __hip_atomic_load((p), __ATOMIC_RELAXED, __HIP_MEMORY_SCOPE_AGENT)
#define ASTORE(p, v) __hip_atomic_store((p), (v), __ATOMIC_RELAXED, __HIP_MEMORY_SCOPE_AGENT)

template <int CTRL>
__device__ __forceinline__ float dpp_add(float m) {
    int t = __builtin_amdgcn_update_dpp(0, __builtin_bit_cast(int, m), CTRL, 0xF, 0xF, true);
    return m + __builtin_bit_cast(float, t);
}
// pair-merged butterfly: returns row-2k sum on even lanes / row-2k+1 on odd
__device__ __forceinline__ float red2(float a, float c, int lane) {
    a = dpp_add<0xB1>(a);
    c = dpp_add<0xB1>(c);
    float m = (lane & 1) ? c : a;
    m = dpp_add<0x122>(m);
    m = dpp_add<0x124>(m);
    m = dpp_add<0x128>(m);
    m += __shfl_xor(m, 16);
    m += __shfl_xor(m, 32);
    return m;
}

// ---------------------------------------------------------------------------
// gx = X @ Wih^T + bih
// ---------------------------------------------------------------------------
__global__ __launch_bounds__(256) void gemm_gx(
    const float* __restrict__ X, const float* __restrict__ Wih,
    const float* __restrict__ bih, float* __restrict__ gxo, int shift_relu)
{
    __shared__ float xs[16][128];
    const int tid = threadIdx.x;
    const int m0  = blockIdx.x * 16;
    const int c   = blockIdx.y * 256 + tid;

    for (int i = tid; i < 16 * 128; i += 256) {
        const int r = i >> 7, k = i & 127;
        int srow = m0 + r;
        if (shift_relu) srow = (srow == 0) ? 0 : (srow - 1);
        float v = X[(size_t)srow * Vv + k];
        if (shift_relu) v = fmaxf(v, 0.f);
        xs[r][k] = v;
    }
    __syncthreads();

    const float4* wp = (const float4*)(Wih + (size_t)c * Vv);
    float4 wr[32];
#pragma unroll
    for (int q = 0; q < 32; ++q) wr[q] = wp[q];
    const float bb = bih[c];

    for (int m = 0; m < 16; ++m) {
        const float4* xp = (const float4*)xs[m];
        float acc = bb;
#pragma unroll
        for (int q = 0; q < 32; ++q) {
            const float4 x4 = xp[q];
            acc = fmaf(wr[q].x, x4.x, acc); acc = fmaf(wr[q].y, x4.y, acc);
            acc = fmaf(wr[q].z, x4.z, acc); acc = fmaf(wr[q].w, x4.w, acc);
        }
        gxo[(size_t)(m0 + m) * G3 + c] = acc;
    }
}

// ---------------------------------------------------------------------------
// Split-role persistent GRU scan (r10 structure) + latency-chain cuts:
// - SELF-SUBSTITUTION: lanes 0-3 splice their own just-computed (value,tag)
//   pair into the poll vector instead of loading it. ownpk is INITIALIZED BY
//   LOADING the init record (slot S0-1) so the decoder picks up the encoder's
//   final h0 (r12 bug: hardcoded 0 broke the decoder's first tick).
// - END-OF-TICK PRIME: after publishing tick t, issue the poll loads for the
//   next tick's slot; late blocks find data already in registers. Race-free:
//   slot t&63 can only hold tag t or t-64 (publish skew <= 1).
// - h0 ring 64 slots; layer-1 watermark gate every 32 ticks (slack 16).
// ---------------------------------------------------------------------------
__global__ __launch_bounds__(64, 1) void seq2(
    const float* __restrict__ gx,
    const float* __restrict__ Whh0, const float* __restrict__ Wih1,
    const float* __restrict__ Whh1,
    const float* __restrict__ bhh0, const float* __restrict__ bih1,
    const float* __restrict__ bhh1,
    unsigned long long* __restrict__ rec,
    float* __restrict__ ys)
{
    const int bid = blockIdx.x, lane = threadIdx.x;
    unsigned long long* h0rec = rec;
    unsigned long long* h1rec = rec + H1OFF;

    if (bid < 128) {
        // ================= layer 0 =================
        const int e0 = 4 * bid;
        int off[8];
#pragma unroll
        for (int j = 0; j < 8; ++j) off[j] = (e0 + lane + 64 * j) & 511;

        float w[12][8];   // rows r = 4*g + i  (Whh0)
#pragma unroll
        for (int g = 0; g < 3; ++g)
#pragma unroll
            for (int i = 0; i < 4; ++i) {
                const float* row = Whh0 + (size_t)(g * Hh + e0 + i) * Hh;
#pragma unroll
                for (int j = 0; j < 8; ++j) w[g * 4 + i][j] = row[off[j]];
            }

        float b_r = 0.f, b_z = 0.f, b_n = 0.f;
        if (lane < 4) {
            const int e = e0 + lane;
            b_r = bhh0[e]; b_z = bhh0[Hh + e]; b_n = bhh0[2 * Hh + e];
        }
        float xr = 0.f, xz = 0.f, xn = 0.f;
        if (lane < 4) {
            xr = gx[e0 + lane]; xz = gx[Hh + e0 + lane]; xn = gx[2 * Hh + e0 + lane];
        }

        // own pair "published last tick": LOAD from init record (decoder's
        // h0(-1) is the encoder final state delivered by handoff!)
        unsigned long long ownpk = ALOAD(h0rec + (size_t)(S0 - 1) * 512 + e0 + (lane & 3));
        unsigned long long pr[8];
        {   // prime tick 0's slot (63, init tag -1)
            const unsigned long long* rp0 = h0rec + (size_t)(S0 - 1) * 512;
#pragma unroll
            for (int j = 0; j < 8; ++j) pr[j] = ALOAD(rp0 + off[j]);
        }

        for (int t = 0; t < LL; ++t) {
            const int need = t - 1;
            const unsigned long long* rp = h0rec + (size_t)((t + S0 - 1) & (S0 - 1)) * 512;
            unsigned long long p[8];
#pragma unroll
            for (int j = 0; j < 8; ++j) p[j] = pr[j];
            if (lane < 4) p[0] = ownpk;
            int ok = 1;
#pragma unroll
            for (int j = 0; j < 8; ++j) ok &= (pair_tag(p[j]) >= need);
            while (!__all(ok)) {
#pragma unroll
                for (int j = 0; j < 8; ++j) p[j] = ALOAD(rp + off[j]);
                if (lane < 4) p[0] = ownpk;
                ok = 1;
#pragma unroll
                for (int j = 0; j < 8; ++j) ok &= (pair_tag(p[j]) >= need);
            }

            // layer-1 watermark gate, once per 32 ticks (16-tick slack)
            if ((t & 31) == 0) {
                const int gneed = t - 16;
                const unsigned long long* gp = h1rec + (size_t)(t & (S1 - 1)) * 512;
                int gok;
                do {
                    gok = 1;
#pragma unroll
                    for (int j = 0; j < 8; ++j) {
                        const unsigned long long q = ALOAD(gp + ((lane + 64 * j) & 511));
                        gok &= (pair_tag(q) >= gneed);
                    }
                } while (!__all(gok));
            }

            // prefetch next gx row (hides under next spin)
            float nxr = 0.f, nxz = 0.f, nxn = 0.f;
            if (lane < 4 && t + 1 < LL) {
                const size_t gb = (size_t)(t + 1) * G3 + e0 + lane;
                nxr = gx[gb]; nxz = gx[gb + Hh]; nxn = gx[gb + 2 * Hh];
            }

            float h0v[8];
#pragma unroll
            for (int j = 0; j < 8; ++j) h0v[j] = pair_val(p[j]);

            float acc[12];
#pragma unroll
            for (int r = 0; r < 12; ++r) acc[r] = 0.f;
#pragma unroll
            for (int j = 0; j < 8; ++j)
#pragma unroll
                for (int r = 0; r < 12; ++r) acc[r] = fmaf(w[r][j], h0v[j], acc[r]);

            float sred[6];
#pragma unroll
            for (int k = 0; k < 6; ++k) sred[k] = red2(acc[2 * k], acc[2 * k + 1], lane);

            if (lane < 4) {
                const int i2 = lane >> 1;
                const float rg = sigm(xr + sred[i2] + b_r);
                const float zg = sigm(xz + sred[2 + i2] + b_z);
                const float ng = tanha(xn + rg * (sred[4 + i2] + b_n));
                const float hnew = (1.f - zg) * ng + zg * h0v[0];
                ownpk = packpair(hnew, t);
                ASTORE(h0rec + (size_t)(t & (S0 - 1)) * 512 + e0 + lane, ownpk);
            }

            // prime next tick's slot (t & 63): late blocks detect instantly
            {
                const unsigned long long* rpn = h0rec + (size_t)(t & (S0 - 1)) * 512;
#pragma unroll
                for (int j = 0; j < 8; ++j) pr[j] = ALOAD(rpn + off[j]);
            }
            xr = nxr; xz = nxz; xn = nxn;
        }
    } else {
        // ================= layer 1 =================
        const int e0 = 4 * (bid - 128);
        int off[8];
#pragma unroll
        for (int j = 0; j < 8; ++j) off[j] = (e0 + lane + 64 * j) & 511;

        float wA[12][8], wB[12][8];   // Wih1, Whh1; rows r = 4*g + i
#pragma unroll
        for (int g = 0; g < 3; ++g)
#pragma unroll
            for (int i = 0; i < 4; ++i) {
                const float* rowA = Wih1 + (size_t)(g * Hh + e0 + i) * Hh;
                const float* rowB = Whh1 + (size_t)(g * Hh + e0 + i) * Hh;
#pragma unroll
                for (int j = 0; j < 8; ++j) {
                    wA[g * 4 + i][j] = rowA[off[j]];
                    wB[g * 4 + i][j] = rowB[off[j]];
                }
            }

        float b_r = 0.f, b_z = 0.f, b_n1 = 0.f, b_n2 = 0.f;
        if (lane < 4) {
            const int e = e0 + lane;
            b_r  = bih1[e] + bhh1[e];
            b_z  = bih1[Hh + e] + bhh1[Hh + e];
            b_n1 = bih1[2 * Hh + e];
            b_n2 = bhh1[2 * Hh + e];
        }

        // own h1(-1) pair from the init record (value differs enc vs dec)
        unsigned long long ownpk1 = ALOAD(h1rec + (size_t)(S1 - 1) * 512 + e0 + (lane & 3));
        unsigned long long pr0[8], pr1[8];
        {   // prime tick 0: h0 slot 0 (not yet written -> fails), h1 slot 3 (init)
            const unsigned long long* a = h0rec;
            const unsigned long long* b = h1rec + (size_t)(S1 - 1) * 512;
#pragma unroll
            for (int j = 0; j < 8; ++j) pr0[j] = ALOAD(a + off[j]);
#pragma unroll
            for (int j = 0; j < 8; ++j) pr1[j] = ALOAD(b + off[j]);
        }

        for (int t = 0; t < LL; ++t) {
            const unsigned long long* rp0 = h0rec + (size_t)(t & (S0 - 1)) * 512;
            const unsigned long long* rp1 = h1rec + (size_t)((t + S1 - 1) & (S1 - 1)) * 512;
            unsigned long long p0[8], p1[8];
#pragma unroll
            for (int j = 0; j < 8; ++j) { p0[j] = pr0[j]; p1[j] = pr1[j]; }
            if (lane < 4) p1[0] = ownpk1;
            int ok = 1;
#pragma unroll
            for (int j = 0; j < 8; ++j)
                ok &= (pair_tag(p0[j]) >= t) & (pair_tag(p1[j]) >= t - 1);
            while (!__all(ok)) {
#pragma unroll
                for (int j = 0; j < 8; ++j) p0[j] = ALOAD(rp0 + off[j]);
#pragma unroll
                for (int j = 0; j < 8; ++j) p1[j] = ALOAD(rp1 + off[j]);
                if (lane < 4) p1[0] = ownpk1;
                ok = 1;
#pragma unroll
                for (int j = 0; j < 8; ++j)
                    ok &= (pair_tag(p0[j]) >= t) & (pair_tag(p1[j]) >= t - 1);
            }

            float h0v[8], h1v[8];
#pragma unroll
            for (int j = 0; j < 8; ++j) { h0v[j] = pair_val(p0[j]); h1v[j] = pair_val(p1[j]); }

            // acc[0..3] r-gate (A+B), [4..7] z (A+B), [8..11] nA, [12..15] nB
            float acc[16];
#pragma unroll
            for (int r = 0; r < 16; ++r) acc[r] = 0.f;
#pragma unroll
            for (int j = 0; j < 8; ++j) {
#pragma unroll
                for (int r = 0; r < 8; ++r) {
                    acc[r] = fmaf(wA[r][j], h0v[j], acc[r]);
                    acc[r] = fmaf(wB[r][j], h1v[j], acc[r]);
                }
#pragma unroll
                for (int i = 0; i < 4; ++i) {
                    acc[8 + i]  = fmaf(wA[8 + i][j], h0v[j], acc[8 + i]);
                    acc[12 + i] = fmaf(wB[8 + i][j], h1v[j], acc[12 + i]);
                }
            }

            float sred[8];
#pragma unroll
            for (int k = 0; k < 8; ++k) sred[k] = red2(acc[2 * k], acc[2 * k + 1], lane);

            if (lane < 4) {
                const int i2 = lane >> 1;
                const float rg = sigm(sred[i2] + b_r);
                const float zg = sigm(sred[2 + i2] + b_z);
                const float ng = tanha(sred[4 + i2] + b_n1 + rg * (sred[6 + i2] + b_n2));
                const float hnew = (1.f - zg) * ng + zg * h1v[0];
                ownpk1 = packpair(hnew, t);
                ASTORE(h1rec + (size_t)(t & (S1 - 1)) * 512 + e0 + lane, ownpk1);
                if (ys) ys[(size_t)t * Hh + e0 + lane] = hnew;
            }

            // prime next tick: h0(t+1) slot, h1(t) slot
            {
                const unsigned long long* a = h0rec + (size_t)((t + 1) & (S0 - 1)) * 512;
                const unsigned long long* b = h1rec + (size_t)(t & (S1 - 1)) * 512;
#pragma unroll
                for (int j = 0; j < 8; ++j) pr0[j] = ALOAD(a + off[j]);
#pragma unroll
                for (int j = 0; j < 8; ++j) pr1[j] = ALOAD(b + off[j]);
            }
        }
    }
}

// ---------------------------------------------------------------------------
// WoutT + encoder record init. h0 ring: slot 63 = (0, tag -1), others -100.
// h1 ring: slot 3 = (0, tag -1), slots 0..2 = tags -4,-3,-2.
// ---------------------------------------------------------------------------
__global__ __launch_bounds__(256) void transposeW(const float* __restrict__ W,
                                                  float* __restrict__ WT,
                                                  unsigned long long* __restrict__ encr)
{
    const int i = blockIdx.x * 256 + threadIdx.x;  // 0..65535
    WT[(i & 511) * 128 + (i >> 9)] = W[i];
    if (i < S0 * 512) {
        const int slot = i >> 9;
        ASTORE(encr + i, packpair(0.f, (slot == S0 - 1) ? -1 : -100));
    }
    if (i < S1 * 512) {
        const int slot = i >> 9;
        ASTORE(encr + H1OFF + i, packpair(0.f, (slot == S1 - 1) ? -1 : slot - 4));
    }
}

// ---------------------------------------------------------------------------
// encoder -> decoder handoff. enc h0(8191): slot 8191&63 = 63; enc h1(8191):
// slot 3. Rewrite EVERY decoder slot (stale tags from prior replay must die).
// ---------------------------------------------------------------------------
__global__ __launch_bounds__(256) void handoff(const unsigned long long* __restrict__ encr,
                                               unsigned long long* __restrict__ decr)
{
    const int p = blockIdx.x * 256 + threadIdx.x;  // 0..32767
    {
        const int slot = p >> 9;
        unsigned long long v;
        if (slot == S0 - 1) {
            const unsigned long long src = ALOAD(encr + p);
            v = packpair(pair_val(src), -1);
        } else {
            v = packpair(0.f, -100);
        }
        ASTORE(decr + p, v);
    }
    if (p < S1 * 512) {
        const int slot = p >> 9;
        unsigned long long v;
        if (slot == S1 - 1) {
            const unsigned long long src = ALOAD(encr + H1OFF + p);
            v = packpair(pair_val(src), -1);
        } else {
            v = packpair(0.f, slot - 4);
        }
        ASTORE(decr + H1OFF + p, v);
    }
}

// ---------------------------------------------------------------------------
// out = sigmoid(ys @ Wout^T + bout)
// ---------------------------------------------------------------------------
__global__ __launch_bounds__(128) void out_proj(
    const float* __restrict__ ys, const float* __restrict__ WT,
    const float* __restrict__ bout, float* __restrict__ out)
{
    __shared__ float yss[16][512];
    const int tid = threadIdx.x;
    const int m0  = blockIdx.x * 16;

    for (int i = tid; i < 16 * 512; i += 128)
        yss[i >> 9][i & 511] = ys[(size_t)(m0 + (i >> 9)) * 512 + (i & 511)];
    __syncthreads();

    const int c = tid;
    float acc[16];
    const float b = bout[c];
#pragma unroll
    for (int m = 0; m < 16; ++m) acc[m] = b;

    for (int k4 = 0; k4 < 128; ++k4) {
        const float w0 = WT[(4 * k4 + 0) * 128 + c];
        const float w1 = WT[(4 * k4 + 1) * 128 + c];
        const float w2 = WT[(4 * k4 + 2) * 128 + c];
        const float w3 = WT[(4 * k4 + 3) * 128 + c];
#pragma unroll
        for (int m = 0; m < 16; ++m) {
            const float4 yv = *(const float4*)&yss[m][4 * k4];
            acc[m] = fmaf(w0, yv.x, fmaf(w1, yv.y, fmaf(w2, yv.z, fmaf(w3, yv.w, acc[m]))));
        }
    }
#pragma unroll
    for (int m = 0; m < 16; ++m)
        out[(size_t)(m0 + m) * 128 + c] = 1.f / (1.f + __expf(-acc[m]));
}

// ---------------------------------------------------------------------------
extern "C" void kernel_launch(void* const* d_in, const int* in_sizes, int n_in,
                              void* d_out, int out_size, void* d_ws, size_t ws_size,
                              hipStream_t stream)
{
    const float* src      = (const float*)d_in[0];
    const float* trg      = (const float*)d_in[1];
    const float* eWih0    = (const float*)d_in[2];
    const float* eWhh0    = (const float*)d_in[3];
    const float* ebih0    = (const float*)d_in[4];
    const float* ebhh0    = (const float*)d_in[5];
    const float* eWih1    = (const float*)d_in[6];
    const float* eWhh1    = (const float*)d_in[7];
    const float* ebih1    = (const float*)d_in[8];
    const float* ebhh1    = (const float*)d_in[9];
    const float* dWih0    = (const float*)d_in[10];
    const float* dWhh0    = (const float*)d_in[11];
    const float* dbih0    = (const float*)d_in[12];
    const float* dbhh0    = (const float*)d_in[13];
    const float* dWih1    = (const float*)d_in[14];
    const float* dWhh1    = (const float*)d_in[15];
    const float* dbih1    = (const float*)d_in[16];
    const float* dbhh1    = (const float*)d_in[17];
    const float* Wout     = (const float*)d_in[18];
    const float* bout     = (const float*)d_in[19];

    char* ws = (char*)d_ws;
    float*              gx   = (float*)(ws + OFF_GX);
    float*              ys   = (float*)(ws + OFF_YS);
    unsigned long long* recE = (unsigned long long*)(ws + OFF_RECE);
    unsigned long long* recD = (unsigned long long*)(ws + OFF_RECD);
    float*              WT   = (float*)(ws + OFF_WT);

    hipLaunchKernelGGL(transposeW, dim3(256), dim3(256), 0, stream, Wout, WT, recE);

    // ---- encoder ----
    hipLaunchKernelGGL(gemm_gx, dim3(LL / 16, 6), dim3(256), 0, stream,
                       src, eWih0, ebih0, gx, 0);
    hipLaunchKernelGGL(seq2, dim3(NBK), dim3(64), 0, stream,
                       gx, eWhh0, eWih1, eWhh1, ebhh0, ebih1, ebhh1,
                       recE, (float*)nullptr);

    // ---- handoff + decoder ----
    hipLaunchKernelGGL(handoff, dim3(128), dim3(256), 0, stream, recE, recD);
    hipLaunchKernelGGL(gemm_gx, dim3(LL / 16, 6), dim3(256), 0, stream,
                       trg, dWih0, dbih0, gx, 1);
    hipLaunchKernelGGL(seq2, dim3(NBK), dim3(64), 0, stream,
                       gx, dWhh0, dWih1, dWhh1, dbhh0, dbih1, dbhh1,
                       recD, ys);

    // ---- output projection ----
    hipLaunchKernelGGL(out_proj, dim3(LL / 16), dim3(128), 0, stream,
                       ys, WT, bout, (float*)d_out);

    (void)in_sizes; (void)n_in; (void)out_size; (void)ws_size;
}

// Round 14
// 32273.831 us; speedup vs baseline: 1.5320x; 1.0846x over previous
//
#include <hip/hip_runtime.h>

// Problem constants
#define Hh   512
#define Vv   128
#define LL   8192
#define G3   1536      // 3*H
#define NBK  256       // 128 layer-0 blocks + 128 layer-1 blocks, 64 thr each
#define S0   16        // h0 ring slots (watermark-gated, 8-tick amortized)
#define S1   4         // h1 ring slots (self-bounded skew <= 2)

// workspace layout (bytes). record = h0ring(16*512 pairs) ++ h1ring(4*512)
#define RECBYTES ((S0*512 + S1*512) * 8ull)            // 81,920
#define OFF_GX   0ull                                  // 50,331,648
#define OFF_YS   50331648ull                           // 16,777,216
#define OFF_RECE 67108864ull
#define OFF_RECD (OFF_RECE + RECBYTES)
#define OFF_WT   (OFF_RECD + RECBYTES)                 // 262,144

#define H1OFF (S0*512)   // pair offset of h1 ring within a record

__device__ __forceinline__ float sigm(float x)  { return 1.f / (1.f + __expf(-x)); }
__device__ __forceinline__ float tanha(float x) { return 2.f / (1.f + __expf(-2.f * x)) - 1.f; }

__device__ __forceinline__ unsigned long long packpair(float v, int t) {
    return ((unsigned long long)(unsigned)t << 32) | (unsigned long long)__float_as_uint(v);
}
__device__ __forceinline__ int   pair_tag(unsigned long long p) { return (int)(p >> 32); }
__device__ __forceinline__ float pair_val(unsigned long long p) { return __uint_as_float((unsigned)p); }

template <int CTRL>
__device__ __forceinline__ float dpp_add(float m) {
    int t = __builtin_amdgcn_update_dpp(0, __builtin_bit_cast(int, m), CTRL, 0xF, 0xF, true);
    return m + __builtin_bit_cast(float, t);
}
// pair-merged butterfly: returns row-2k sum on even lanes / row-2k+1 on odd
__device__ __forceinline__ float red2(float a, float c, int lane) {
    a = dpp_add<0xB1>(a);
    c = dpp_add<0xB1>(c);
    float m = (lane & 1) ? c : a;
    m = dpp_add<0x122>(m);
    m = dpp_add<0x124>(m);
    m = dpp_add<0x128>(m);
    m += __shfl_xor(m, 16);
    m += __shfl_xor(m, 32);
    return m;
}

// ---------------------------------------------------------------------------
// gx = X @ Wih^T + bih
// ---------------------------------------------------------------------------
__global__ __launch_bounds__(256) void gemm_gx(
    const float* __restrict__ X, const float* __restrict__ Wih,
    const float* __restrict__ bih, float* __restrict__ gxo, int shift_relu)
{
    __shared__ float xs[16][128];
    const int tid = threadIdx.x;
    const int m0  = blockIdx.x * 16;
    const int c   = blockIdx.y * 256 + tid;

    for (int i = tid; i < 16 * 128; i += 256) {
        const int r = i >> 7, k = i & 127;
        int srow = m0 + r;
        if (shift_relu) srow = (srow == 0) ? 0 : (srow - 1);
        float v = X[(size_t)srow * Vv + k];
        if (shift_relu) v = fmaxf(v, 0.f);
        xs[r][k] = v;
    }
    __syncthreads();

    const float4* wp = (const float4*)(Wih + (size_t)c * Vv);
    float4 wr[32];
#pragma unroll
    for (int q = 0; q < 32; ++q) wr[q] = wp[q];
    const float bb = bih[c];

    for (int m = 0; m < 16; ++m) {
        const float4* xp = (const float4*)xs[m];
        float acc = bb;
#pragma unroll
        for (int q = 0; q < 32; ++q) {
            const float4 x4 = xp[q];
            acc = fmaf(wr[q].x, x4.x, acc); acc = fmaf(wr[q].y, x4.y, acc);
            acc = fmaf(wr[q].z, x4.z, acc); acc = fmaf(wr[q].w, x4.w, acc);
        }
        gxo[(size_t)(m0 + m) * G3 + c] = acc;
    }
}

// ---------------------------------------------------------------------------
// Split-role persistent GRU scan (measured-best r10 structure).
// Blocks 0-127: layer 0 (own h0[4b..4b+3]); blocks 128-255: layer 1.
// h0 ring: 16 slots, slot t&15, tag t. h1 ring: 4 slots. Layer-0 tick t:
// poll h0(t-1) [8 loads/lane], every 8th tick verify layer-1 watermark
// (h1 slot t&3 tag >= t-4; covers publishes t..t+7 destroying slots >= 9
// ticks old), compute c0(t), publish. Layer-1 tick t: poll h0(t) + h1(t-1)
// [h1 a tick old -> usually instant], compute c1(t), publish + ys. All
// pairs self-validating (value,tag); detect = data, fire-and-forget stores.
// ---------------------------------------------------------------------------
__global__ __launch_bounds__(64, 1) void seq2(
    const float* __restrict__ gx,
    const float* __restrict__ Whh0, const float* __restrict__ Wih1,
    const float* __restrict__ Whh1,
    const float* __restrict__ bhh0, const float* __restrict__ bih1,
    const float* __restrict__ bhh1,
    unsigned long long* __restrict__ rec,
    float* __restrict__ ys)
{
    const int bid = blockIdx.x, lane = threadIdx.x;
    unsigned long long* h0rec = rec;
    unsigned long long* h1rec = rec + H1OFF;

    if (bid < 128) {
        // ================= layer 0 =================
        const int e0 = 4 * bid;
        int off[8];
#pragma unroll
        for (int j = 0; j < 8; ++j) off[j] = (e0 + lane + 64 * j) & 511;

        float w[12][8];   // rows r = 4*g + i  (Whh0)
#pragma unroll
        for (int g = 0; g < 3; ++g)
#pragma unroll
            for (int i = 0; i < 4; ++i) {
                const float* row = Whh0 + (size_t)(g * Hh + e0 + i) * Hh;
#pragma unroll
                for (int j = 0; j < 8; ++j) w[g * 4 + i][j] = row[off[j]];
            }

        float b_r = 0.f, b_z = 0.f, b_n = 0.f;
        if (lane < 4) {
            const int e = e0 + lane;
            b_r = bhh0[e]; b_z = bhh0[Hh + e]; b_n = bhh0[2 * Hh + e];
        }
        float xr = 0.f, xz = 0.f, xn = 0.f;
        if (lane < 4) {
            xr = gx[e0 + lane]; xz = gx[Hh + e0 + lane]; xn = gx[2 * Hh + e0 + lane];
        }

        for (int t = 0; t < LL; ++t) {
            // spin on h0(t-1)
            const int need = t - 1;
            const unsigned long long* rp = h0rec + (size_t)((t + S0 - 1) & (S0 - 1)) * 512;
            unsigned long long p[8];
            int ok;
            do {
#pragma unroll
                for (int j = 0; j < 8; ++j)
                    p[j] = __hip_atomic_load(rp + off[j], __ATOMIC_RELAXED, __HIP_MEMORY_SCOPE_AGENT);
                ok = 1;
#pragma unroll
                for (int j = 0; j < 8; ++j) ok &= (pair_tag(p[j]) >= need);
            } while (!__all(ok));

            // layer-1 watermark gate, once per 8 ticks (4-tick slack)
            if ((t & 7) == 0) {
                const int gneed = t - 4;
                const unsigned long long* gp = h1rec + (size_t)(t & (S1 - 1)) * 512;
                int gok;
                do {
                    gok = 1;
#pragma unroll
                    for (int j = 0; j < 8; ++j) {
                        const unsigned long long q = __hip_atomic_load(
                            gp + ((lane + 64 * j) & 511), __ATOMIC_RELAXED, __HIP_MEMORY_SCOPE_AGENT);
                        gok &= (pair_tag(q) >= gneed);
                    }
                } while (!__all(gok));
            }

            // prefetch next gx row (hides under next spin)
            float nxr = 0.f, nxz = 0.f, nxn = 0.f;
            if (lane < 4 && t + 1 < LL) {
                const size_t gb = (size_t)(t + 1) * G3 + e0 + lane;
                nxr = gx[gb]; nxz = gx[gb + Hh]; nxn = gx[gb + 2 * Hh];
            }

            float h0v[8];
#pragma unroll
            for (int j = 0; j < 8; ++j) h0v[j] = pair_val(p[j]);

            float acc[12];
#pragma unroll
            for (int r = 0; r < 12; ++r) acc[r] = 0.f;
#pragma unroll
            for (int j = 0; j < 8; ++j)
#pragma unroll
                for (int r = 0; r < 12; ++r) acc[r] = fmaf(w[r][j], h0v[j], acc[r]);

            float sred[6];
#pragma unroll
            for (int k = 0; k < 6; ++k) sred[k] = red2(acc[2 * k], acc[2 * k + 1], lane);

            if (lane < 4) {
                const int i2 = lane >> 1;
                const float rg = sigm(xr + sred[i2] + b_r);
                const float zg = sigm(xz + sred[2 + i2] + b_z);
                const float ng = tanha(xn + rg * (sred[4 + i2] + b_n));
                const float hnew = (1.f - zg) * ng + zg * h0v[0];
                __hip_atomic_store(h0rec + (size_t)(t & (S0 - 1)) * 512 + e0 + lane,
                                   packpair(hnew, t), __ATOMIC_RELAXED, __HIP_MEMORY_SCOPE_AGENT);
            }
            xr = nxr; xz = nxz; xn = nxn;
        }
    } else {
        // ================= layer 1 =================
        const int e0 = 4 * (bid - 128);
        int off[8];
#pragma unroll
        for (int j = 0; j < 8; ++j) off[j] = (e0 + lane + 64 * j) & 511;

        float wA[12][8], wB[12][8];   // Wih1, Whh1; rows r = 4*g + i
#pragma unroll
        for (int g = 0; g < 3; ++g)
#pragma unroll
            for (int i = 0; i < 4; ++i) {
                const float* rowA = Wih1 + (size_t)(g * Hh + e0 + i) * Hh;
                const float* rowB = Whh1 + (size_t)(g * Hh + e0 + i) * Hh;
#pragma unroll
                for (int j = 0; j < 8; ++j) {
                    wA[g * 4 + i][j] = rowA[off[j]];
                    wB[g * 4 + i][j] = rowB[off[j]];
                }
            }

        float b_r = 0.f, b_z = 0.f, b_n1 = 0.f, b_n2 = 0.f;
        if (lane < 4) {
            const int e = e0 + lane;
            b_r  = bih1[e] + bhh1[e];
            b_z  = bih1[Hh + e] + bhh1[Hh + e];
            b_n1 = bih1[2 * Hh + e];
            b_n2 = bhh1[2 * Hh + e];
        }

        for (int t = 0; t < LL; ++t) {
            // poll h0(t) (fresh -> the real wait) + h1(t-1) (a tick old)
            const unsigned long long* rp0 = h0rec + (size_t)(t & (S0 - 1)) * 512;
            const unsigned long long* rp1 = h1rec + (size_t)((t + S1 - 1) & (S1 - 1)) * 512;
            unsigned long long p0[8], p1[8];
            int ok;
            do {
#pragma unroll
                for (int j = 0; j < 8; ++j)
                    p0[j] = __hip_atomic_load(rp0 + off[j], __ATOMIC_RELAXED, __HIP_MEMORY_SCOPE_AGENT);
#pragma unroll
                for (int j = 0; j < 8; ++j)
                    p1[j] = __hip_atomic_load(rp1 + off[j], __ATOMIC_RELAXED, __HIP_MEMORY_SCOPE_AGENT);
                ok = 1;
#pragma unroll
                for (int j = 0; j < 8; ++j)
                    ok &= (pair_tag(p0[j]) >= t) & (pair_tag(p1[j]) >= t - 1);
            } while (!__all(ok));

            float h0v[8], h1v[8];
#pragma unroll
            for (int j = 0; j < 8; ++j) { h0v[j] = pair_val(p0[j]); h1v[j] = pair_val(p1[j]); }

            // acc[0..3] r-gate (A+B), [4..7] z (A+B), [8..11] nA, [12..15] nB
            float acc[16];
#pragma unroll
            for (int r = 0; r < 16; ++r) acc[r] = 0.f;
#pragma unroll
            for (int j = 0; j < 8; ++j) {
#pragma unroll
                for (int r = 0; r < 8; ++r) {
                    acc[r] = fmaf(wA[r][j], h0v[j], acc[r]);
                    acc[r] = fmaf(wB[r][j], h1v[j], acc[r]);
                }
#pragma unroll
                for (int i = 0; i < 4; ++i) {
                    acc[8 + i]  = fmaf(wA[8 + i][j], h0v[j], acc[8 + i]);
                    acc[12 + i] = fmaf(wB[8 + i][j], h1v[j], acc[12 + i]);
                }
            }

            float sred[8];
#pragma unroll
            for (int k = 0; k < 8; ++k) sred[k] = red2(acc[2 * k], acc[2 * k + 1], lane);

            if (lane < 4) {
                const int i2 = lane >> 1;
                const float rg = sigm(sred[i2] + b_r);
                const float zg = sigm(sred[2 + i2] + b_z);
                const float ng = tanha(sred[4 + i2] + b_n1 + rg * (sred[6 + i2] + b_n2));
                const float hnew = (1.f - zg) * ng + zg * h1v[0];
                if (ys) ys[(size_t)t * Hh + e0 + lane] = hnew;
                __hip_atomic_store(h1rec + (size_t)(t & (S1 - 1)) * 512 + e0 + lane,
                                   packpair(hnew, t), __ATOMIC_RELAXED, __HIP_MEMORY_SCOPE_AGENT);
            }
        }
    }
}

// ---------------------------------------------------------------------------
// WoutT + encoder record init. h0 ring: slot 15 = (0, tag -1), others tag
// -100. h1 ring: slot 3 = (0, tag -1), slots 0..2 = tags -4,-3,-2.
// ---------------------------------------------------------------------------
__global__ __launch_bounds__(256) void transposeW(const float* __restrict__ W,
                                                  float* __restrict__ WT,
                                                  unsigned long long* __restrict__ encr)
{
    const int i = blockIdx.x * 256 + threadIdx.x;  // 0..65535
    WT[(i & 511) * 128 + (i >> 9)] = W[i];
    if (i < S0 * 512) {
        const int slot = i >> 9;
        __hip_atomic_store(encr + i, packpair(0.f, (slot == S0 - 1) ? -1 : -100),
                           __ATOMIC_RELAXED, __HIP_MEMORY_SCOPE_AGENT);
    }
    if (i < S1 * 512) {
        const int slot = i >> 9;
        __hip_atomic_store(encr + H1OFF + i, packpair(0.f, (slot == S1 - 1) ? -1 : slot - 4),
                           __ATOMIC_RELAXED, __HIP_MEMORY_SCOPE_AGENT);
    }
}

// ---------------------------------------------------------------------------
// encoder -> decoder handoff. enc h0(8191) is in h0 slot 8191&15 = 15; enc
// h1(8191) in h1 slot 3. Rewrite EVERY decoder slot (stale tags from prior
// replay must die): h0 slot15 = (enc val, -1), others -100; h1 slot3 =
// (enc val, -1), slots 0..2 tags -4,-3,-2.
// ---------------------------------------------------------------------------
__global__ __launch_bounds__(256) void handoff(const unsigned long long* __restrict__ encr,
                                               unsigned long long* __restrict__ decr)
{
    const int p = blockIdx.x * 256 + threadIdx.x;  // 0..8191
    {
        const int slot = p >> 9;
        unsigned long long v;
        if (slot == S0 - 1) {
            const unsigned long long src = __hip_atomic_load(
                encr + p, __ATOMIC_RELAXED, __HIP_MEMORY_SCOPE_AGENT);
            v = packpair(pair_val(src), -1);
        } else {
            v = packpair(0.f, -100);
        }
        __hip_atomic_store(decr + p, v, __ATOMIC_RELAXED, __HIP_MEMORY_SCOPE_AGENT);
    }
    if (p < S1 * 512) {
        const int slot = p >> 9;
        unsigned long long v;
        if (slot == S1 - 1) {
            const unsigned long long src = __hip_atomic_load(
                encr + H1OFF + p, __ATOMIC_RELAXED, __HIP_MEMORY_SCOPE_AGENT);
            v = packpair(pair_val(src), -1);
        } else {
            v = packpair(0.f, slot - 4);
        }
        __hip_atomic_store(decr + H1OFF + p, v, __ATOMIC_RELAXED, __HIP_MEMORY_SCOPE_AGENT);
    }
}

// ---------------------------------------------------------------------------
// out = sigmoid(ys @ Wout^T + bout)
// ---------------------------------------------------------------------------
__global__ __launch_bounds__(128) void out_proj(
    const float* __restrict__ ys, const float* __restrict__ WT,
    const float* __restrict__ bout, float* __restrict__ out)
{
    __shared__ float yss[16][512];
    const int tid = threadIdx.x;
    const int m0  = blockIdx.x * 16;

    for (int i = tid; i < 16 * 512; i += 128)
        yss[i >> 9][i & 511] = ys[(size_t)(m0 + (i >> 9)) * 512 + (i & 511)];
    __syncthreads();

    const int c = tid;
    float acc[16];
    const float b = bout[c];
#pragma unroll
    for (int m = 0; m < 16; ++m) acc[m] = b;

    for (int k4 = 0; k4 < 128; ++k4) {
        const float w0 = WT[(4 * k4 + 0) * 128 + c];
        const float w1 = WT[(4 * k4 + 1) * 128 + c];
        const float w2 = WT[(4 * k4 + 2) * 128 + c];
        const float w3 = WT[(4 * k4 + 3) * 128 + c];
#pragma unroll
        for (int m = 0; m < 16; ++m) {
            const float4 yv = *(const float4*)&yss[m][4 * k4];
            acc[m] = fmaf(w0, yv.x, fmaf(w1, yv.y, fmaf(w2, yv.z, fmaf(w3, yv.w, acc[m]))));
        }
    }
#pragma unroll
    for (int m = 0; m < 16; ++m)
        out[(size_t)(m0 + m) * 128 + c] = 1.f / (1.f + __expf(-acc[m]));
}

// ---------------------------------------------------------------------------
extern "C" void kernel_launch(void* const* d_in, const int* in_sizes, int n_in,
                              void* d_out, int out_size, void* d_ws, size_t ws_size,
                              hipStream_t stream)
{
    const float* src      = (const float*)d_in[0];
    const float* trg      = (const float*)d_in[1];
    const float* eWih0    = (const float*)d_in[2];
    const float* eWhh0    = (const float*)d_in[3];
    const float* ebih0    = (const float*)d_in[4];
    const float* ebhh0    = (const float*)d_in[5];
    const float* eWih1    = (const float*)d_in[6];
    const float* eWhh1    = (const float*)d_in[7];
    const float* ebih1    = (const float*)d_in[8];
    const float* ebhh1    = (const float*)d_in[9];
    const float* dWih0    = (const float*)d_in[10];
    const float* dWhh0    = (const float*)d_in[11];
    const float* dbih0    = (const float*)d_in[12];
    const float* dbhh0    = (const float*)d_in[13];
    const float* dWih1    = (const float*)d_in[14];
    const float* dWhh1    = (const float*)d_in[15];
    const float* dbih1    = (const float*)d_in[16];
    const float* dbhh1    = (const float*)d_in[17];
    const float* Wout     = (const float*)d_in[18];
    const float* bout     = (const float*)d_in[19];

    char* ws = (char*)d_ws;
    float*              gx   = (float*)(ws + OFF_GX);
    float*              ys   = (float*)(ws + OFF_YS);
    unsigned long long* recE = (unsigned long long*)(ws + OFF_RECE);
    unsigned long long* recD = (unsigned long long*)(ws + OFF_RECD);
    float*              WT   = (float*)(ws + OFF_WT);

    hipLaunchKernelGGL(transposeW, dim3(256), dim3(256), 0, stream, Wout, WT, recE);

    // ---- encoder ----
    hipLaunchKernelGGL(gemm_gx, dim3(LL / 16, 6), dim3(256), 0, stream,
                       src, eWih0, ebih0, gx, 0);
    hipLaunchKernelGGL(seq2, dim3(NBK), dim3(64), 0, stream,
                       gx, eWhh0, eWih1, eWhh1, ebhh0, ebih1, ebhh1,
                       recE, (float*)nullptr);

    // ---- handoff + decoder ----
    hipLaunchKernelGGL(handoff, dim3(32), dim3(256), 0, stream, recE, recD);
    hipLaunchKernelGGL(gemm_gx, dim3(LL / 16, 6), dim3(256), 0, stream,
                       trg, dWih0, dbih0, gx, 1);
    hipLaunchKernelGGL(seq2, dim3(NBK), dim3(64), 0, stream,
                       gx, dWhh0, dWih1, dWhh1, dbhh0, dbih1, dbhh1,
                       recD, ys);

    // ---- output projection ----
    hipLaunchKernelGGL(out_proj, dim3(LL / 16), dim3(128), 0, stream,
                       ys, WT, bout, (float*)d_out);

    (void)in_sizes; (void)n_in; (void)out_size; (void)ws_size;
}